// Round 12
// baseline (168.795 us; speedup 1.0000x reference)
//
#include <hip/hip_runtime.h>
#include <math.h>

#define EE 300
#define KP 320     // bf16 row stride (10 k-steps of 32)
#define LDSW 328   // padded LDS row stride in shorts
#define QQ 64
#define DD 4096
#define NEG 0.01f

typedef __attribute__((ext_vector_type(8))) short short8;
typedef __attribute__((ext_vector_type(4))) float f32x4;
typedef unsigned short ushort_t;

__device__ inline ushort_t f2bf(float f) {
  unsigned u = __builtin_bit_cast(unsigned, f);
  u += 0x7fff + ((u >> 16) & 1);   // RNE
  return (ushort_t)(u >> 16);
}
__device__ inline float bf2f(ushort_t h) {
  return __builtin_bit_cast(float, (unsigned)h << 16);
}
__device__ inline void top5_insert(float* t, float v) {
  if (v > t[4]) {
    t[4] = v;
    #pragma unroll
    for (int j = 4; j > 0; --j)
      if (t[j] > t[j - 1]) { float tmp = t[j]; t[j] = t[j - 1]; t[j - 1] = tmp; }
  }
}
// xor-merge sorted-5 lists across 64 lanes -> lane-uniform sorted-5
__device__ inline void wave_merge5(float* t5) {
  #pragma unroll
  for (int mask = 1; mask < 64; mask <<= 1) {
    float a[5], bb[5];
    #pragma unroll
    for (int j = 0; j < 5; ++j) { a[j] = t5[j]; bb[j] = __shfl_xor(t5[j], mask); }
    int ia = 0, ib = 0;
    #pragma unroll
    for (int j = 0; j < 5; ++j) t5[j] = (a[ia] >= bb[ib]) ? a[ia++] : bb[ib++];
  }
}

// ======= launch 1: gather+convert | weight frags | oh partial pool ==========
#define GATHER_ROWS (66 + 4098 + 4098)           // 8262
#define GATHER_BLOCKS ((GATHER_ROWS + 3) / 4)    // 2066
#define WT_BLOCKS 143                            // 570 frags / 4
#define OHPOOL_BLOCKS 256                        // 2 srcs x 128 chunks
#define PREP_BLOCKS (GATHER_BLOCKS + WT_BLOCKS + OHPOOL_BLOCKS)

__global__ __launch_bounds__(256) void prep(
    const float* __restrict__ emb, const int* __restrict__ question,
    const int* __restrict__ doc1, const int* __restrict__ doc2,
    const float* __restrict__ conv_w,
    const float* __restrict__ doc1_sim, const float* __restrict__ doc2_sim,
    ushort_t* __restrict__ qbe, ushort_t* __restrict__ d1be, ushort_t* __restrict__ d2be,
    ushort_t* __restrict__ qbc, ushort_t* __restrict__ d1bc, ushort_t* __restrict__ d2bc,
    ushort_t* __restrict__ wt2,
    float* __restrict__ nq2, float* __restrict__ nd12, float* __restrict__ nd22,
    float* __restrict__ pt5) {
  __shared__ float strip[64][33];
  int b = blockIdx.x;
  int tid = threadIdx.x;
  int wv = tid >> 6, lane = tid & 63;
  if (b < GATHER_BLOCKS) {
    int g = b * 4 + wv;
    if (g >= GATHER_ROWS) return;
    int t, row;
    if (g < 66)             { t = 0; row = g; }
    else if (g < 66 + 4098) { t = 1; row = g - 66; }
    else                    { t = 2; row = g - 4164; }
    const int* idx = t == 0 ? question : (t == 1 ? doc1 : doc2);
    int L = t == 0 ? QQ : DD;
    ushort_t* be = t == 0 ? qbe : (t == 1 ? d1be : d2be);
    ushort_t* bc = t == 0 ? qbc : (t == 1 ? d1bc : d2bc);
    float* nrm2 = t == 0 ? nq2 : (t == 1 ? nd12 : nd22);
    const short8 z8 = (short8){0, 0, 0, 0, 0, 0, 0, 0};
    if (row == 0 || row == L + 1) {            // zero guard rows (40 slots)
      if (lane < 40) *(short8*)(be + (size_t)row * KP + lane * 8) = z8;
      return;
    }
    int r = row - 1;
    const float* src = emb + (size_t)idx[r] * EE;   // 16B-aligned (1200B rows)
    float ss = 0.f;
    if (lane < 37) {                           // elems [lane*8, lane*8+8)
      f32x4 v0 = *(const f32x4*)(src + lane * 8);
      f32x4 v1 = *(const f32x4*)(src + lane * 8 + 4);
      short8 hb;
      #pragma unroll
      for (int e = 0; e < 4; ++e) { hb[e] = (short)f2bf(v0[e]); ss += v0[e] * v0[e]; }
      #pragma unroll
      for (int e = 0; e < 4; ++e) { hb[4 + e] = (short)f2bf(v1[e]); ss += v1[e] * v1[e]; }
      *(short8*)(be + (size_t)row * KP + lane * 8) = hb;
    } else if (lane == 37) {                   // elems 296..299 + 4 zeros
      f32x4 v0 = *(const f32x4*)(src + 296);
      short8 hb = z8;
      #pragma unroll
      for (int e = 0; e < 4; ++e) { hb[e] = (short)f2bf(v0[e]); ss += v0[e] * v0[e]; }
      *(short8*)(be + (size_t)row * KP + 296) = hb;
    } else if (lane < 40) {                    // K-pad slots 38,39
      *(short8*)(be + (size_t)row * KP + lane * 8) = z8;
    }
    if (lane < 20) bc[(size_t)r * KP + 300 + lane] = 0;   // conv-out K-pad
    #pragma unroll
    for (int o = 32; o; o >>= 1) ss += __shfl_xor(ss, o);
    if (lane == 0) nrm2[r] = ss;               // SQUARED norm
  } else if (b < GATHER_BLOCKS + WT_BLOCKS) {
    int f = (b - GATHER_BLOCKS) * 4 + wv;
    if (f >= 570) return;
    int ks = f % 10, n = (f / 10) % 19, tap = f / 190;
    int o = n * 16 + (lane & 15);
    int kbase = ks * 32 + (lane >> 4) * 8;
    ushort_t* dst = wt2 + (size_t)f * 512 + lane * 8;
    #pragma unroll
    for (int e = 0; e < 8; ++e) {
      int k = kbase + e;
      float v = (o < EE && k < EE) ? conv_w[((size_t)o * EE + k) * 3 + tap] : 0.f;
      dst[e] = f2bf(v);
    }
  } else {
    // ---- oh partial pooling: coalesced 32-row x 64-q chunk of doc_sim ----
    int ob = b - (GATHER_BLOCKS + WT_BLOCKS);
    int o = ob >> 7, chunk = ob & 127;
    int ps = o ? 3 : 0;
    const float* dsim = o ? doc2_sim : doc1_sim;   // [D][Q]
    int l0 = chunk * 32;
    int r = tid >> 3, q0 = (tid & 7) * 8;
    const float* srcp = dsim + (size_t)(l0 + r) * QQ + q0;
    f32x4 v0 = *(const f32x4*)srcp;
    f32x4 v1 = *(const f32x4*)(srcp + 4);
    #pragma unroll
    for (int e = 0; e < 4; ++e) strip[q0 + e][r] = v0[e];
    #pragma unroll
    for (int e = 0; e < 4; ++e) strip[q0 + 4 + e][r] = v1[e];
    __syncthreads();
    if (tid < 64) {
      float t5[5] = {-1e30f, -1e30f, -1e30f, -1e30f, -1e30f};
      #pragma unroll
      for (int l = 0; l < 32; ++l) top5_insert(t5, strip[tid][l]);
      float* dst = pt5 + (((size_t)ps * QQ + tid) * 128 + chunk) * 8;
      *(f32x4*)dst = (f32x4){t5[0], t5[1], t5[2], t5[3]};
      *(f32x4*)(dst + 4) = (f32x4){t5[4], -1e30f, -1e30f, -1e30f};
    }
  }
}

// ===== launch 2: conv1d(E,E,3,SAME)+bias+leaky+residual, 32-row M-tiles =====
// 516 blocks (m0, yh halves). Norm^2/qw partials per column-half stored
// non-atomically: ncH[yh][row], qwaccH[yh][row]; consumers sum halves.
__global__ __launch_bounds__(256) void conv_mfma(
    const ushort_t* __restrict__ wt2, const float* __restrict__ bias,
    const float* __restrict__ qw_w,
    const ushort_t* __restrict__ qbe, const ushort_t* __restrict__ d1be,
    const ushort_t* __restrict__ d2be,
    ushort_t* __restrict__ qbc, ushort_t* __restrict__ d1bc,
    ushort_t* __restrict__ d2bc,
    float* __restrict__ nqcH, float* __restrict__ nd1cH, float* __restrict__ nd2cH,
    float* __restrict__ qwaccH) {
  __shared__ ushort_t lds[34 * LDSW];
  __shared__ float normbuf[4][32];
  __shared__ float qwbuf[4][32];
  int bx = blockIdx.x;
  int t, m0, yh;
  if (bx < 4) { t = 0; m0 = (bx >> 1) * 32; yh = bx & 1; }
  else {
    int i = bx - 4;
    t = 1 + (i >> 8);
    int j = i & 255;
    m0 = (j >> 1) * 32; yh = j & 1;
  }
  const ushort_t* be = t == 0 ? qbe : (t == 1 ? d1be : d2be);
  ushort_t* bc = t == 0 ? qbc : (t == 1 ? d1bc : d2bc);
  float* ncH = t == 0 ? nqcH : (t == 1 ? nd1cH : nd2cH);
  int ncs = t == 0 ? QQ : DD;
  int tid = threadIdx.x;
  for (int s = tid; s < 34 * 40; s += 256) {
    int row = s / 40, col = s - row * 40;
    *(short8*)(&lds[row * LDSW + col * 8]) =
        *(const short8*)(be + (size_t)(m0 + row) * KP + col * 8);
  }
  __syncthreads();
  int wv = tid >> 6, lane = tid & 63, mrow = lane & 15, g = lane >> 4;
  int nstart, ncnt;
  if (yh == 0) { nstart = (wv < 2) ? 3 * wv : 2 * wv + 2; ncnt = (wv < 2) ? 3 : 2; }
  else         { nstart = (wv == 0) ? 10 : 2 * wv + 11;   ncnt = (wv == 0) ? 3 : 2; }
  f32x4 acc[3][2];
  #pragma unroll
  for (int j = 0; j < 3; ++j)
    #pragma unroll
    for (int h = 0; h < 2; ++h) acc[j][h] = (f32x4){0.f, 0.f, 0.f, 0.f};

  for (int tap = 0; tap < 3; ++tap) {
    const ushort_t* alo = &lds[(mrow + tap) * LDSW + g * 8];
    #pragma unroll
    for (int ks = 0; ks < 10; ++ks) {
      short8 a0 = *(const short8*)(alo + ks * 32);
      short8 a1 = *(const short8*)(alo + 16 * LDSW + ks * 32);
      #pragma unroll
      for (int j = 0; j < 3; ++j) {
        if (j < ncnt) {
          short8 bfr = *(const short8*)(wt2 +
              (size_t)((tap * 19 + nstart + j) * 10 + ks) * 512 + lane * 8);
          acc[j][0] = __builtin_amdgcn_mfma_f32_16x16x32_bf16(a0, bfr, acc[j][0], 0, 0, 0);
          acc[j][1] = __builtin_amdgcn_mfma_f32_16x16x32_bf16(a1, bfr, acc[j][1], 0, 0, 0);
        }
      }
    }
  }
  float ss[2][4] = {{0.f,0.f,0.f,0.f},{0.f,0.f,0.f,0.f}};
  float yq[2][4] = {{0.f,0.f,0.f,0.f},{0.f,0.f,0.f,0.f}};
  #pragma unroll
  for (int j = 0; j < 3; ++j) {
    if (j < ncnt) {
      int col = (nstart + j) * 16 + mrow;
      if (col < EE) {
        float bcol = bias[col];
        float qwc = (t == 0) ? qw_w[col] : 0.f;
        #pragma unroll
        for (int h = 0; h < 2; ++h) {
          #pragma unroll
          for (int r = 0; r < 4; ++r) {
            int lrow = h * 16 + g * 4 + r;
            float y = acc[j][h][r] + bcol;
            y = (y >= 0.f) ? y : NEG * y;
            y += bf2f(lds[(1 + lrow) * LDSW + col]);
            bc[(size_t)(m0 + lrow) * KP + col] = f2bf(y);
            ss[h][r] += y * y;
            if (t == 0) yq[h][r] += y * qwc;
          }
        }
      }
    }
  }
  #pragma unroll
  for (int h = 0; h < 2; ++h) {
    #pragma unroll
    for (int r = 0; r < 4; ++r) {
      float s = ss[h][r];
      s += __shfl_xor(s, 1); s += __shfl_xor(s, 2);
      s += __shfl_xor(s, 4); s += __shfl_xor(s, 8);
      float sq = yq[h][r];
      sq += __shfl_xor(sq, 1); sq += __shfl_xor(sq, 2);
      sq += __shfl_xor(sq, 4); sq += __shfl_xor(sq, 8);
      if (mrow == 0) {
        normbuf[wv][h * 16 + g * 4 + r] = s;
        qwbuf[wv][h * 16 + g * 4 + r] = sq;
      }
    }
  }
  __syncthreads();
  if (tid < 32) {
    ncH[(size_t)yh * ncs + m0 + tid] =
        normbuf[0][tid] + normbuf[1][tid] + normbuf[2][tid] + normbuf[3][tid];
    if (t == 0)
      qwaccH[yh * QQ + m0 + tid] =
          qwbuf[0][tid] + qwbuf[1][tid] + qwbuf[2][tid] + qwbuf[3][tid];
  }
}

// ====== launch 3: sims GEMM + per-chunk partial top5 (no global sims) =======
// 512 blocks: s = b>>7 (0=ins_d1 1=ins_d2 2=sen_d1 3=sen_d2), chunk = b&127.
__global__ __launch_bounds__(256) void sim_pool(
    const ushort_t* __restrict__ qbe, const ushort_t* __restrict__ d1be,
    const ushort_t* __restrict__ d2be,
    const ushort_t* __restrict__ qbc, const ushort_t* __restrict__ d1bc,
    const ushort_t* __restrict__ d2bc,
    const float* __restrict__ nq2, const float* __restrict__ nd12,
    const float* __restrict__ nd22, const float* __restrict__ nqcH,
    const float* __restrict__ nd1cH, const float* __restrict__ nd2cH,
    float* __restrict__ pt5) {
  __shared__ ushort_t ldsB[32 * LDSW];
  __shared__ float strip[64][33];
  int s = blockIdx.x >> 7, chunk = blockIdx.x & 127;
  int ps = (s == 0) ? 1 : (s == 1) ? 4 : (s == 2) ? 2 : 5;
  int l0 = chunk * 32;
  const ushort_t* A = (s < 2) ? qbe + KP : qbc;
  const ushort_t* B = s == 0 ? d1be + KP : s == 1 ? d2be + KP
                    : s == 2 ? d1bc : d2bc;
  int tid = threadIdx.x;
  for (int i = tid; i < 32 * 40; i += 256) {
    int row = i / 40, col = i - row * 40;
    *(short8*)(&ldsB[row * LDSW + col * 8]) =
        *(const short8*)(B + (size_t)(l0 + row) * KP + col * 8);
  }
  __syncthreads();
  int wv = tid >> 6, lane = tid & 63, mrow = lane & 15, g = lane >> 4;
  f32x4 acc[2];
  acc[0] = (f32x4){0.f, 0.f, 0.f, 0.f};
  acc[1] = (f32x4){0.f, 0.f, 0.f, 0.f};
  const ushort_t* arow = A + (size_t)(wv * 16 + mrow) * KP + g * 8;
  #pragma unroll
  for (int ks = 0; ks < 10; ++ks) {
    short8 a = *(const short8*)(arow + ks * 32);
    #pragma unroll
    for (int n = 0; n < 2; ++n) {
      short8 bfr = *(const short8*)(&ldsB[(n * 16 + mrow) * LDSW + g * 8 + ks * 32]);
      acc[n] = __builtin_amdgcn_mfma_f32_16x16x32_bf16(a, bfr, acc[n], 0, 0, 0);
    }
  }
  #pragma unroll
  for (int n = 0; n < 2; ++n) {
    int l = n * 16 + mrow;
    float nb2v = (s == 0) ? nd12[l0 + l]
               : (s == 1) ? nd22[l0 + l]
               : (s == 2) ? (nd1cH[l0 + l] + nd1cH[DD + l0 + l])
                          : (nd2cH[l0 + l] + nd2cH[DD + l0 + l]);
    float inb = rsqrtf(nb2v);
    #pragma unroll
    for (int r = 0; r < 4; ++r) {
      int q = wv * 16 + g * 4 + r;
      float na2v = (s < 2) ? nq2[q] : (nqcH[q] + nqcH[QQ + q]);
      strip[q][l] = acc[n][r] * rsqrtf(na2v) * inb;
    }
  }
  __syncthreads();
  if (tid < 64) {
    float t5[5] = {-1e30f, -1e30f, -1e30f, -1e30f, -1e30f};
    #pragma unroll
    for (int l = 0; l < 32; ++l) top5_insert(t5, strip[tid][l]);
    float* dst = pt5 + (((size_t)ps * QQ + tid) * 128 + chunk) * 8;
    *(f32x4*)dst = (f32x4){t5[0], t5[1], t5[2], t5[3]};
    *(f32x4*)(dst + 4) = (f32x4){t5[4], -1e30f, -1e30f, -1e30f};
  }
}

// ==== launch 4: merge all partials + softmax + MLP + epilogue (one block) ===
// 1024 threads = 16 waves; wave handles 24 (src,q) pairs. Lane reads 2 chunks
// (64B contiguous), wave_merge5, stage in LDS; wave 0 runs the epilogue.
__global__ __launch_bounds__(1024) void mergefinal(
    const float* __restrict__ pt5,
    const float* __restrict__ qwaccH, const float* __restrict__ idf,
    const int* __restrict__ question, const float* __restrict__ qw_w,
    const float* __restrict__ qw_b, const float* __restrict__ lin1_w,
    const float* __restrict__ lin2_w, const float* __restrict__ out_w,
    const float* __restrict__ gaf, const float* __restrict__ baf,
    float* __restrict__ out5) {
  __shared__ float poolL[6][QQ][2];
  int tid = threadIdx.x, wv = tid >> 6, lane = tid & 63;
  for (int i = 0; i < 24; ++i) {
    int widx = i * 16 + wv;                  // 0..383
    int src = widx >> 6, q = widx & 63;
    const float* p0 = pt5 + (((size_t)src * QQ + q) * 128 + 2 * lane) * 8;
    f32x4 v0 = *(const f32x4*)p0;
    f32x4 v1 = *(const f32x4*)(p0 + 4);
    f32x4 v2 = *(const f32x4*)(p0 + 8);
    f32x4 v3 = *(const f32x4*)(p0 + 12);
    float t5[5] = {v0[0], v0[1], v0[2], v0[3], v1[0]};   // chunk0 sorted-5
    top5_insert(t5, v2[0]); top5_insert(t5, v2[1]); top5_insert(t5, v2[2]);
    top5_insert(t5, v2[3]); top5_insert(t5, v3[0]);      // chunk1
    wave_merge5(t5);
    if (lane == 0) {
      float sm = t5[0] + t5[1] + t5[2] + t5[3] + t5[4];
      poolL[src][q][0] = t5[0];
      poolL[src][q][1] = sm * 0.2f;
    }
  }
  __syncthreads();
  if (tid < 64) {
    int q = tid;
    float s = qwaccH[q] + qwaccH[QQ + q] + qw_b[0] + idf[question[q]] * qw_w[EE];
    float m = s;
    #pragma unroll
    for (int o = 32; o; o >>= 1) m = fmaxf(m, __shfl_xor(m, o));
    float e = expf(s - m);
    float se = e;
    #pragma unroll
    for (int o = 32; o; o >>= 1) se += __shfl_xor(se, o);
    float qwgt = e / se;
    float emit[2];
    for (int doc = 0; doc < 2; ++doc) {
      float temp[6];
      #pragma unroll
      for (int j = 0; j < 3; ++j) {
        temp[2 * j]     = poolL[doc * 3 + j][q][0];
        temp[2 * j + 1] = poolL[doc * 3 + j][q][1];
      }
      float lo = 0.f;
      #pragma unroll
      for (int r = 0; r < 8; ++r) {
        float h = 0.f;
        #pragma unroll
        for (int c = 0; c < 6; ++c) h += lin1_w[r * 6 + c] * temp[c];
        h = (h >= 0.f) ? h : NEG * h;
        lo += lin2_w[r] * h;
      }
      lo *= qwgt;
      #pragma unroll
      for (int o = 32; o; o >>= 1) lo += __shfl_xor(lo, o);
      emit[doc] = lo / (float)QQ;
    }
    if (q == 0) {
      float good = out_w[0] * gaf[0] + out_w[1] * gaf[1] + out_w[2] * gaf[2] +
                   out_w[3] * gaf[3] + out_w[4] * emit[0];
      float bad  = out_w[0] * baf[0] + out_w[1] * baf[1] + out_w[2] * baf[2] +
                   out_w[3] * baf[3] + out_w[4] * emit[1];
      float l1 = fmaxf(0.f, -(good - bad) + 1.f);
      out5[0] = l1; out5[1] = good; out5[2] = bad; out5[3] = l1; out5[4] = l1;
    }
  }
}

extern "C" void kernel_launch(void* const* d_in, const int* in_sizes, int n_in,
                              void* d_out, int out_size, void* d_ws, size_t ws_size,
                              hipStream_t stream) {
  (void)in_sizes; (void)n_in; (void)out_size; (void)ws_size;
  const int* question   = (const int*)d_in[0];
  const int* doc1       = (const int*)d_in[1];
  const int* doc2       = (const int*)d_in[2];
  const float* doc1_sim = (const float*)d_in[3];
  const float* doc2_sim = (const float*)d_in[4];
  const float* gaf      = (const float*)d_in[5];
  const float* baf      = (const float*)d_in[6];
  const float* emb      = (const float*)d_in[7];
  const float* idf      = (const float*)d_in[8];
  const float* conv_w   = (const float*)d_in[9];
  const float* conv_b   = (const float*)d_in[10];
  const float* qw_w     = (const float*)d_in[11];
  const float* qw_b     = (const float*)d_in[12];
  const float* lin1_w   = (const float*)d_in[13];
  const float* lin2_w   = (const float*)d_in[14];
  const float* out_w    = (const float*)d_in[15];
  float* out = (float*)d_out;

  char* p = (char*)d_ws;
  ushort_t* qbe  = (ushort_t*)p; p += (size_t)(QQ + 2) * KP * 2;
  ushort_t* d1be = (ushort_t*)p; p += (size_t)(DD + 2) * KP * 2;
  ushort_t* d2be = (ushort_t*)p; p += (size_t)(DD + 2) * KP * 2;
  ushort_t* qbc  = (ushort_t*)p; p += (size_t)QQ * KP * 2;
  ushort_t* d1bc = (ushort_t*)p; p += (size_t)DD * KP * 2;
  ushort_t* d2bc = (ushort_t*)p; p += (size_t)DD * KP * 2;
  ushort_t* wt2  = (ushort_t*)p; p += (size_t)570 * 512 * 2;
  float* nq2    = (float*)p; p += QQ * 4;
  float* nd12   = (float*)p; p += DD * 4;
  float* nd22   = (float*)p; p += DD * 4;
  float* nqcH   = (float*)p; p += 2 * QQ * 4;    // [yh][row] halves
  float* nd1cH  = (float*)p; p += 2 * DD * 4;
  float* nd2cH  = (float*)p; p += 2 * DD * 4;
  float* qwaccH = (float*)p; p += 2 * QQ * 4;
  float* pt5    = (float*)p; p += (size_t)6 * QQ * 128 * 8 * 4;

  prep<<<PREP_BLOCKS, 256, 0, stream>>>(
      emb, question, doc1, doc2, conv_w, doc1_sim, doc2_sim,
      qbe, d1be, d2be, qbc, d1bc, d2bc, wt2,
      nq2, nd12, nd22, pt5);

  conv_mfma<<<516, 256, 0, stream>>>(
      wt2, conv_b, qw_w, qbe, d1be, d2be, qbc, d1bc, d2bc,
      nqcH, nd1cH, nd2cH, qwaccH);

  sim_pool<<<512, 256, 0, stream>>>(
      qbe, d1be, d2be, qbc, d1bc, d2bc,
      nq2, nd12, nd22, nqcH, nd1cH, nd2cH, pt5);

  mergefinal<<<1, 1024, 0, stream>>>(
      pt5, qwaccH, idf, question, qw_w, qw_b,
      lin1_w, lin2_w, out_w, gaf, baf, out);
}

// Round 13
// 61.773 us; speedup vs baseline: 2.7325x; 2.7325x over previous
//
#include <hip/hip_runtime.h>
#include <math.h>

#define EE 300
#define KP 320     // bf16 row stride (10 k-steps of 32)
#define LDSW 328   // padded LDS row stride in shorts
#define QQ 64
#define DD 4096
#define NEG 0.01f

typedef __attribute__((ext_vector_type(8))) short short8;
typedef __attribute__((ext_vector_type(4))) float f32x4;
typedef unsigned short ushort_t;

__device__ inline ushort_t f2bf(float f) {
  unsigned u = __builtin_bit_cast(unsigned, f);
  u += 0x7fff + ((u >> 16) & 1);   // RNE
  return (ushort_t)(u >> 16);
}
__device__ inline float bf2f(ushort_t h) {
  return __builtin_bit_cast(float, (unsigned)h << 16);
}
__device__ inline void top5_insert(float* t, float v) {
  if (v > t[4]) {
    t[4] = v;
    #pragma unroll
    for (int j = 4; j > 0; --j)
      if (t[j] > t[j - 1]) { float tmp = t[j]; t[j] = t[j - 1]; t[j - 1] = tmp; }
  }
}

// ======= launch 1: gather+convert | weight frags | oh partial pool ==========
#define GATHER_ROWS (66 + 4098 + 4098)           // 8262
#define GATHER_BLOCKS ((GATHER_ROWS + 3) / 4)    // 2066
#define WT_BLOCKS 143                            // 570 frags / 4
#define OHPOOL_BLOCKS 256                        // 2 srcs x 128 chunks
#define PREP_BLOCKS (GATHER_BLOCKS + WT_BLOCKS + OHPOOL_BLOCKS)

__global__ __launch_bounds__(256) void prep(
    const float* __restrict__ emb, const int* __restrict__ question,
    const int* __restrict__ doc1, const int* __restrict__ doc2,
    const float* __restrict__ conv_w,
    const float* __restrict__ doc1_sim, const float* __restrict__ doc2_sim,
    ushort_t* __restrict__ qbe, ushort_t* __restrict__ d1be, ushort_t* __restrict__ d2be,
    ushort_t* __restrict__ qbc, ushort_t* __restrict__ d1bc, ushort_t* __restrict__ d2bc,
    ushort_t* __restrict__ wt2,
    float* __restrict__ nq2, float* __restrict__ nd12, float* __restrict__ nd22,
    float* __restrict__ pt5) {
  __shared__ float strip[64][33];
  int b = blockIdx.x;
  int tid = threadIdx.x;
  int wv = tid >> 6, lane = tid & 63;
  if (b < GATHER_BLOCKS) {
    int g = b * 4 + wv;
    if (g >= GATHER_ROWS) return;
    int t, row;
    if (g < 66)             { t = 0; row = g; }
    else if (g < 66 + 4098) { t = 1; row = g - 66; }
    else                    { t = 2; row = g - 4164; }
    const int* idx = t == 0 ? question : (t == 1 ? doc1 : doc2);
    int L = t == 0 ? QQ : DD;
    ushort_t* be = t == 0 ? qbe : (t == 1 ? d1be : d2be);
    ushort_t* bc = t == 0 ? qbc : (t == 1 ? d1bc : d2bc);
    float* nrm2 = t == 0 ? nq2 : (t == 1 ? nd12 : nd22);
    const short8 z8 = (short8){0, 0, 0, 0, 0, 0, 0, 0};
    if (row == 0 || row == L + 1) {            // zero guard rows (40 slots)
      if (lane < 40) *(short8*)(be + (size_t)row * KP + lane * 8) = z8;
      return;
    }
    int r = row - 1;
    const float* src = emb + (size_t)idx[r] * EE;   // 16B-aligned (1200B rows)
    float ss = 0.f;
    if (lane < 37) {                           // elems [lane*8, lane*8+8)
      f32x4 v0 = *(const f32x4*)(src + lane * 8);
      f32x4 v1 = *(const f32x4*)(src + lane * 8 + 4);
      short8 hb;
      #pragma unroll
      for (int e = 0; e < 4; ++e) { hb[e] = (short)f2bf(v0[e]); ss += v0[e] * v0[e]; }
      #pragma unroll
      for (int e = 0; e < 4; ++e) { hb[4 + e] = (short)f2bf(v1[e]); ss += v1[e] * v1[e]; }
      *(short8*)(be + (size_t)row * KP + lane * 8) = hb;
    } else if (lane == 37) {                   // elems 296..299 + 4 zeros
      f32x4 v0 = *(const f32x4*)(src + 296);
      short8 hb = z8;
      #pragma unroll
      for (int e = 0; e < 4; ++e) { hb[e] = (short)f2bf(v0[e]); ss += v0[e] * v0[e]; }
      *(short8*)(be + (size_t)row * KP + 296) = hb;
    } else if (lane < 40) {                    // K-pad slots 38,39
      *(short8*)(be + (size_t)row * KP + lane * 8) = z8;
    }
    if (lane < 20) bc[(size_t)r * KP + 300 + lane] = 0;   // conv-out K-pad
    #pragma unroll
    for (int o = 32; o; o >>= 1) ss += __shfl_xor(ss, o);
    if (lane == 0) nrm2[r] = ss;               // SQUARED norm
  } else if (b < GATHER_BLOCKS + WT_BLOCKS) {
    int f = (b - GATHER_BLOCKS) * 4 + wv;
    if (f >= 570) return;
    int ks = f % 10, n = (f / 10) % 19, tap = f / 190;
    int o = n * 16 + (lane & 15);
    int kbase = ks * 32 + (lane >> 4) * 8;
    ushort_t* dst = wt2 + (size_t)f * 512 + lane * 8;
    #pragma unroll
    for (int e = 0; e < 8; ++e) {
      int k = kbase + e;
      float v = (o < EE && k < EE) ? conv_w[((size_t)o * EE + k) * 3 + tap] : 0.f;
      dst[e] = f2bf(v);
    }
  } else {
    // ---- oh partial pooling: coalesced 32-row x 64-q chunk of doc_sim ----
    int ob = b - (GATHER_BLOCKS + WT_BLOCKS);
    int o = ob >> 7, chunk = ob & 127;
    int ps = o ? 3 : 0;
    const float* dsim = o ? doc2_sim : doc1_sim;   // [D][Q]
    int l0 = chunk * 32;
    int r = tid >> 3, q0 = (tid & 7) * 8;
    const float* srcp = dsim + (size_t)(l0 + r) * QQ + q0;
    f32x4 v0 = *(const f32x4*)srcp;
    f32x4 v1 = *(const f32x4*)(srcp + 4);
    #pragma unroll
    for (int e = 0; e < 4; ++e) strip[q0 + e][r] = v0[e];
    #pragma unroll
    for (int e = 0; e < 4; ++e) strip[q0 + 4 + e][r] = v1[e];
    __syncthreads();
    if (tid < 64) {
      float t5[5] = {-1e30f, -1e30f, -1e30f, -1e30f, -1e30f};
      #pragma unroll
      for (int l = 0; l < 32; ++l) top5_insert(t5, strip[tid][l]);
      float* dst = pt5 + (((size_t)ps * QQ + tid) * 128 + chunk) * 8;
      *(f32x4*)dst = (f32x4){t5[0], t5[1], t5[2], t5[3]};
      *(f32x4*)(dst + 4) = (f32x4){t5[4], -1e30f, -1e30f, -1e30f};
    }
  }
}

// ==== launch 2: conv1d(E,E,3,SAME), 64-row M-tiles x quarter-N (516 blk) ====
// Each B fragment feeds 4 MFMAs; wt2 L2 traffic halves vs 32-row tiles while
// keeping 2 blocks/CU. Norm^2/qw partials per quarter: ncQ[yq][row].
__global__ __launch_bounds__(256) void conv_mfma(
    const ushort_t* __restrict__ wt2, const float* __restrict__ bias,
    const float* __restrict__ qw_w,
    const ushort_t* __restrict__ qbe, const ushort_t* __restrict__ d1be,
    const ushort_t* __restrict__ d2be,
    ushort_t* __restrict__ qbc, ushort_t* __restrict__ d1bc,
    ushort_t* __restrict__ d2bc,
    float* __restrict__ nqcQ, float* __restrict__ nd1cQ, float* __restrict__ nd2cQ,
    float* __restrict__ qwaccQ) {
  __shared__ ushort_t lds[66 * LDSW];          // 43.3 KB
  __shared__ float normbuf[4][64];
  __shared__ float qwbuf[4][64];
  int bx = blockIdx.x;
  int t, m0, yq;
  if (bx < 4) { t = 0; m0 = 0; yq = bx; }
  else {
    int i = bx - 4;                            // 0..511
    t = 1 + (i >> 8);
    int j = i & 255;                           // (m-tile<<2) | yq
    m0 = (j >> 2) * 64; yq = j & 3;
  }
  const ushort_t* be = t == 0 ? qbe : (t == 1 ? d1be : d2be);
  ushort_t* bc = t == 0 ? qbc : (t == 1 ? d1bc : d2bc);
  float* ncQ = t == 0 ? nqcQ : (t == 1 ? nd1cQ : nd2cQ);
  int L = t == 0 ? QQ : DD;
  int tid = threadIdx.x;
  for (int s = tid; s < 66 * 40; s += 256) {
    int row = s / 40, col = s - row * 40;
    *(short8*)(&lds[row * LDSW + col * 8]) =
        *(const short8*)(be + (size_t)(m0 + row) * KP + col * 8);
  }
  __syncthreads();
  int wv = tid >> 6, lane = tid & 63, mrow = lane & 15, g = lane >> 4;
  // quarter yq owns tiles yq*5 .. min(yq*5+4, 18); wave wv takes nt0 = yq*5+wv,
  // wave 0 additionally takes nt1 = yq*5+4 when it exists (yq<3).
  int nt0 = yq * 5 + wv;
  int nt1 = yq * 5 + 4;
  bool v1 = (wv == 0) && (nt1 <= 18);
  f32x4 acc[2][4];
  #pragma unroll
  for (int j = 0; j < 2; ++j)
    #pragma unroll
    for (int h = 0; h < 4; ++h) acc[j][h] = (f32x4){0.f, 0.f, 0.f, 0.f};

  for (int tap = 0; tap < 3; ++tap) {
    const ushort_t* alo = &lds[(mrow + tap) * LDSW + g * 8];
    #pragma unroll
    for (int ks = 0; ks < 10; ++ks) {
      short8 a[4];
      #pragma unroll
      for (int h = 0; h < 4; ++h)
        a[h] = *(const short8*)(alo + h * 16 * LDSW + ks * 32);
      short8 b0 = *(const short8*)(wt2 +
          (size_t)((tap * 19 + nt0) * 10 + ks) * 512 + lane * 8);
      #pragma unroll
      for (int h = 0; h < 4; ++h)
        acc[0][h] = __builtin_amdgcn_mfma_f32_16x16x32_bf16(a[h], b0, acc[0][h], 0, 0, 0);
      if (v1) {
        short8 b1 = *(const short8*)(wt2 +
            (size_t)((tap * 19 + nt1) * 10 + ks) * 512 + lane * 8);
        #pragma unroll
        for (int h = 0; h < 4; ++h)
          acc[1][h] = __builtin_amdgcn_mfma_f32_16x16x32_bf16(a[h], b1, acc[1][h], 0, 0, 0);
      }
    }
  }
  float ss[4][4] = {{0.f},{0.f},{0.f},{0.f}};
  float yqd[4][4] = {{0.f},{0.f},{0.f},{0.f}};
  #pragma unroll
  for (int j = 0; j < 2; ++j) {
    if (j == 0 || v1) {
      int col = (j == 0 ? nt0 : nt1) * 16 + mrow;
      if (col < EE) {
        float bcol = bias[col];
        float qwc = (t == 0) ? qw_w[col] : 0.f;
        #pragma unroll
        for (int h = 0; h < 4; ++h) {
          #pragma unroll
          for (int r = 0; r < 4; ++r) {
            int lrow = h * 16 + g * 4 + r;     // 0..63
            float y = acc[j][h][r] + bcol;
            y = (y >= 0.f) ? y : NEG * y;
            y += bf2f(lds[(1 + lrow) * LDSW + col]);
            bc[(size_t)(m0 + lrow) * KP + col] = f2bf(y);
            ss[h][r] += y * y;
            if (t == 0) yqd[h][r] += y * qwc;
          }
        }
      }
    }
  }
  #pragma unroll
  for (int h = 0; h < 4; ++h) {
    #pragma unroll
    for (int r = 0; r < 4; ++r) {
      float s = ss[h][r];
      s += __shfl_xor(s, 1); s += __shfl_xor(s, 2);
      s += __shfl_xor(s, 4); s += __shfl_xor(s, 8);
      float sq = yqd[h][r];
      sq += __shfl_xor(sq, 1); sq += __shfl_xor(sq, 2);
      sq += __shfl_xor(sq, 4); sq += __shfl_xor(sq, 8);
      if (mrow == 0) {
        normbuf[wv][h * 16 + g * 4 + r] = s;
        qwbuf[wv][h * 16 + g * 4 + r] = sq;
      }
    }
  }
  __syncthreads();
  if (tid < 64) {
    ncQ[(size_t)yq * L + m0 + tid] =
        normbuf[0][tid] + normbuf[1][tid] + normbuf[2][tid] + normbuf[3][tid];
    if (t == 0)
      qwaccQ[yq * QQ + tid] =
          qwbuf[0][tid] + qwbuf[1][tid] + qwbuf[2][tid] + qwbuf[3][tid];
  }
}

// ====== launch 3: sims GEMM + per-chunk partial top5 (no global sims) =======
// 512 blocks: s = b>>7 (0=ins_d1 1=ins_d2 2=sen_d1 3=sen_d2), chunk = b&127.
__global__ __launch_bounds__(256) void sim_pool(
    const ushort_t* __restrict__ qbe, const ushort_t* __restrict__ d1be,
    const ushort_t* __restrict__ d2be,
    const ushort_t* __restrict__ qbc, const ushort_t* __restrict__ d1bc,
    const ushort_t* __restrict__ d2bc,
    const float* __restrict__ nq2, const float* __restrict__ nd12,
    const float* __restrict__ nd22, const float* __restrict__ nqcQ,
    const float* __restrict__ nd1cQ, const float* __restrict__ nd2cQ,
    float* __restrict__ pt5) {
  __shared__ ushort_t ldsB[32 * LDSW];
  __shared__ float strip[64][33];
  int s = blockIdx.x >> 7, chunk = blockIdx.x & 127;
  int ps = (s == 0) ? 1 : (s == 1) ? 4 : (s == 2) ? 2 : 5;
  int l0 = chunk * 32;
  const ushort_t* A = (s < 2) ? qbe + KP : qbc;
  const ushort_t* B = s == 0 ? d1be + KP : s == 1 ? d2be + KP
                    : s == 2 ? d1bc : d2bc;
  int tid = threadIdx.x;
  for (int i = tid; i < 32 * 40; i += 256) {
    int row = i / 40, col = i - row * 40;
    *(short8*)(&ldsB[row * LDSW + col * 8]) =
        *(const short8*)(B + (size_t)(l0 + row) * KP + col * 8);
  }
  __syncthreads();
  int wv = tid >> 6, lane = tid & 63, mrow = lane & 15, g = lane >> 4;
  f32x4 acc[2];
  acc[0] = (f32x4){0.f, 0.f, 0.f, 0.f};
  acc[1] = (f32x4){0.f, 0.f, 0.f, 0.f};
  const ushort_t* arow = A + (size_t)(wv * 16 + mrow) * KP + g * 8;
  #pragma unroll
  for (int ks = 0; ks < 10; ++ks) {
    short8 a = *(const short8*)(arow + ks * 32);
    #pragma unroll
    for (int n = 0; n < 2; ++n) {
      short8 bfr = *(const short8*)(&ldsB[(n * 16 + mrow) * LDSW + g * 8 + ks * 32]);
      acc[n] = __builtin_amdgcn_mfma_f32_16x16x32_bf16(a, bfr, acc[n], 0, 0, 0);
    }
  }
  #pragma unroll
  for (int n = 0; n < 2; ++n) {
    int l = n * 16 + mrow;
    float nb2v;
    if (s == 0)      nb2v = nd12[l0 + l];
    else if (s == 1) nb2v = nd22[l0 + l];
    else if (s == 2) nb2v = nd1cQ[l0 + l] + nd1cQ[DD + l0 + l] +
                            nd1cQ[2 * DD + l0 + l] + nd1cQ[3 * DD + l0 + l];
    else             nb2v = nd2cQ[l0 + l] + nd2cQ[DD + l0 + l] +
                            nd2cQ[2 * DD + l0 + l] + nd2cQ[3 * DD + l0 + l];
    float inb = rsqrtf(nb2v);
    #pragma unroll
    for (int r = 0; r < 4; ++r) {
      int q = wv * 16 + g * 4 + r;
      float na2v = (s < 2) ? nq2[q]
                 : (nqcQ[q] + nqcQ[QQ + q] + nqcQ[2 * QQ + q] + nqcQ[3 * QQ + q]);
      strip[q][l] = acc[n][r] * rsqrtf(na2v) * inb;
    }
  }
  __syncthreads();
  if (tid < 64) {
    float t5[5] = {-1e30f, -1e30f, -1e30f, -1e30f, -1e30f};
    #pragma unroll
    for (int l = 0; l < 32; ++l) top5_insert(t5, strip[tid][l]);
    float* dst = pt5 + (((size_t)ps * QQ + tid) * 128 + chunk) * 8;
    *(f32x4*)dst = (f32x4){t5[0], t5[1], t5[2], t5[3]};
    *(f32x4*)(dst + 4) = (f32x4){t5[4], -1e30f, -1e30f, -1e30f};
  }
}

// ========= launch 4: merge 128 partials per (src,q) -> pool ================
// 96 blocks x 4 waves; wave = one (src,q). Coalesced 4KB read per wave.
__global__ __launch_bounds__(256) void merge(
    const float* __restrict__ pt5, float* __restrict__ pool) {
  int widx = blockIdx.x * 4 + (threadIdx.x >> 6);
  int lane = threadIdx.x & 63;
  int src = widx >> 6, q = widx & 63;
  const float* p0 = pt5 + (((size_t)src * QQ + q) * 128 + 2 * lane) * 8;
  float t5[5] = {-1e30f, -1e30f, -1e30f, -1e30f, -1e30f};
  #pragma unroll
  for (int c = 0; c < 2; ++c)
    #pragma unroll
    for (int j = 0; j < 5; ++j) top5_insert(t5, p0[c * 8 + j]);
  #pragma unroll
  for (int mask = 1; mask < 64; mask <<= 1) {
    float a[5], bb[5];
    #pragma unroll
    for (int j = 0; j < 5; ++j) { a[j] = t5[j]; bb[j] = __shfl_xor(t5[j], mask); }
    int ia = 0, ib = 0;
    #pragma unroll
    for (int j = 0; j < 5; ++j) t5[j] = (a[ia] >= bb[ib]) ? a[ia++] : bb[ib++];
  }
  if (lane == 0) {
    float sm = t5[0] + t5[1] + t5[2] + t5[3] + t5[4];
    pool[((size_t)src * QQ + q) * 2 + 0] = t5[0];
    pool[((size_t)src * QQ + q) * 2 + 1] = sm * 0.2f;
  }
}

// ================= launch 5: softmax + MLP + epilogue (one wave) ============
__global__ void final_kernel(
    const float* __restrict__ qwaccQ, const float* __restrict__ idf,
    const int* __restrict__ question, const float* __restrict__ qw_w,
    const float* __restrict__ qw_b, const float* __restrict__ pool,
    const float* __restrict__ lin1_w, const float* __restrict__ lin2_w,
    const float* __restrict__ out_w, const float* __restrict__ gaf,
    const float* __restrict__ baf, float* __restrict__ out5) {
  int q = threadIdx.x;  // 64 threads = one wave
  float s = qwaccQ[q] + qwaccQ[QQ + q] + qwaccQ[2 * QQ + q] + qwaccQ[3 * QQ + q] +
            qw_b[0] + idf[question[q]] * qw_w[EE];
  float m = s;
  #pragma unroll
  for (int o = 32; o; o >>= 1) m = fmaxf(m, __shfl_xor(m, o));
  float e = expf(s - m);
  float se = e;
  #pragma unroll
  for (int o = 32; o; o >>= 1) se += __shfl_xor(se, o);
  float qwgt = e / se;

  float emit[2];
  for (int doc = 0; doc < 2; ++doc) {
    float temp[6];
    #pragma unroll
    for (int j = 0; j < 3; ++j) {
      temp[2 * j]     = pool[(((size_t)doc * 3 + j) * QQ + q) * 2 + 0];
      temp[2 * j + 1] = pool[(((size_t)doc * 3 + j) * QQ + q) * 2 + 1];
    }
    float lo = 0.f;
    #pragma unroll
    for (int r = 0; r < 8; ++r) {
      float h = 0.f;
      #pragma unroll
      for (int c = 0; c < 6; ++c) h += lin1_w[r * 6 + c] * temp[c];
      h = (h >= 0.f) ? h : NEG * h;
      lo += lin2_w[r] * h;
    }
    lo *= qwgt;
    #pragma unroll
    for (int o = 32; o; o >>= 1) lo += __shfl_xor(lo, o);
    emit[doc] = lo / (float)QQ;
  }
  if (q == 0) {
    float good = out_w[0] * gaf[0] + out_w[1] * gaf[1] + out_w[2] * gaf[2] +
                 out_w[3] * gaf[3] + out_w[4] * emit[0];
    float bad  = out_w[0] * baf[0] + out_w[1] * baf[1] + out_w[2] * baf[2] +
                 out_w[3] * baf[3] + out_w[4] * emit[1];
    float l1 = fmaxf(0.f, -(good - bad) + 1.f);
    out5[0] = l1; out5[1] = good; out5[2] = bad; out5[3] = l1; out5[4] = l1;
  }
}

extern "C" void kernel_launch(void* const* d_in, const int* in_sizes, int n_in,
                              void* d_out, int out_size, void* d_ws, size_t ws_size,
                              hipStream_t stream) {
  (void)in_sizes; (void)n_in; (void)out_size; (void)ws_size;
  const int* question   = (const int*)d_in[0];
  const int* doc1       = (const int*)d_in[1];
  const int* doc2       = (const int*)d_in[2];
  const float* doc1_sim = (const float*)d_in[3];
  const float* doc2_sim = (const float*)d_in[4];
  const float* gaf      = (const float*)d_in[5];
  const float* baf      = (const float*)d_in[6];
  const float* emb      = (const float*)d_in[7];
  const float* idf      = (const float*)d_in[8];
  const float* conv_w   = (const float*)d_in[9];
  const float* conv_b   = (const float*)d_in[10];
  const float* qw_w     = (const float*)d_in[11];
  const float* qw_b     = (const float*)d_in[12];
  const float* lin1_w   = (const float*)d_in[13];
  const float* lin2_w   = (const float*)d_in[14];
  const float* out_w    = (const float*)d_in[15];
  float* out = (float*)d_out;

  char* p = (char*)d_ws;
  ushort_t* qbe  = (ushort_t*)p; p += (size_t)(QQ + 2) * KP * 2;
  ushort_t* d1be = (ushort_t*)p; p += (size_t)(DD + 2) * KP * 2;
  ushort_t* d2be = (ushort_t*)p; p += (size_t)(DD + 2) * KP * 2;
  ushort_t* qbc  = (ushort_t*)p; p += (size_t)QQ * KP * 2;
  ushort_t* d1bc = (ushort_t*)p; p += (size_t)DD * KP * 2;
  ushort_t* d2bc = (ushort_t*)p; p += (size_t)DD * KP * 2;
  ushort_t* wt2  = (ushort_t*)p; p += (size_t)570 * 512 * 2;
  float* nq2    = (float*)p; p += QQ * 4;
  float* nd12   = (float*)p; p += DD * 4;
  float* nd22   = (float*)p; p += DD * 4;
  float* nqcQ   = (float*)p; p += 4 * QQ * 4;    // [yq][row] quarters
  float* nd1cQ  = (float*)p; p += 4 * DD * 4;
  float* nd2cQ  = (float*)p; p += 4 * DD * 4;
  float* qwaccQ = (float*)p; p += 4 * QQ * 4;
  float* pt5    = (float*)p; p += (size_t)6 * QQ * 128 * 8 * 4;
  float* pool   = (float*)p; p += 6 * QQ * 2 * 4;

  prep<<<PREP_BLOCKS, 256, 0, stream>>>(
      emb, question, doc1, doc2, conv_w, doc1_sim, doc2_sim,
      qbe, d1be, d2be, qbc, d1bc, d2bc, wt2,
      nq2, nd12, nd22, pt5);

  conv_mfma<<<516, 256, 0, stream>>>(
      wt2, conv_b, qw_w, qbe, d1be, d2be, qbc, d1bc, d2bc,
      nqcQ, nd1cQ, nd2cQ, qwaccQ);

  sim_pool<<<512, 256, 0, stream>>>(
      qbe, d1be, d2be, qbc, d1bc, d2bc,
      nq2, nd12, nd22, nqcQ, nd1cQ, nd2cQ, pt5);

  merge<<<96, 256, 0, stream>>>(pt5, pool);

  final_kernel<<<1, 64, 0, stream>>>(qwaccQ, idf, question, qw_w, qw_b, pool,
                                     lin1_w, lin2_w, out_w, gaf, baf, out);
}

// Round 14
// 57.243 us; speedup vs baseline: 2.9488x; 1.0791x over previous
//
#include <hip/hip_runtime.h>
#include <math.h>

#define EE 300
#define KP 320     // bf16 row stride (10 k-steps of 32)
#define LDSW 328   // padded LDS row stride in shorts
#define QQ 64
#define DD 4096
#define NEG 0.01f

typedef __attribute__((ext_vector_type(8))) short short8;
typedef __attribute__((ext_vector_type(4))) float f32x4;
typedef unsigned short ushort_t;

__device__ inline ushort_t f2bf(float f) {
  unsigned u = __builtin_bit_cast(unsigned, f);
  u += 0x7fff + ((u >> 16) & 1);   // RNE
  return (ushort_t)(u >> 16);
}
__device__ inline float bf2f(ushort_t h) {
  return __builtin_bit_cast(float, (unsigned)h << 16);
}
__device__ inline void top5_insert(float* t, float v) {
  if (v > t[4]) {
    t[4] = v;
    #pragma unroll
    for (int j = 4; j > 0; --j)
      if (t[j] > t[j - 1]) { float tmp = t[j]; t[j] = t[j - 1]; t[j - 1] = tmp; }
  }
}

// == launch 1: gather+convert | weight frags | zero accum | oh partial pool ==
#define GATHER_ROWS (66 + 4098 + 4098)           // 8262
#define GATHER_BLOCKS ((GATHER_ROWS + 3) / 4)    // 2066
#define WT_BLOCKS 143                            // 570 frags / 4
#define ZERO_BLOCKS 9                            // 8320 floats
#define OHPOOL_BLOCKS 256                        // 2 srcs x 128 chunks
#define PREP_BLOCKS (GATHER_BLOCKS + WT_BLOCKS + ZERO_BLOCKS + OHPOOL_BLOCKS)

__global__ __launch_bounds__(256) void prep(
    const float* __restrict__ emb, const int* __restrict__ question,
    const int* __restrict__ doc1, const int* __restrict__ doc2,
    const float* __restrict__ conv_w,
    const float* __restrict__ doc1_sim, const float* __restrict__ doc2_sim,
    ushort_t* __restrict__ qbe, ushort_t* __restrict__ d1be, ushort_t* __restrict__ d2be,
    ushort_t* __restrict__ qbc, ushort_t* __restrict__ d1bc, ushort_t* __restrict__ d2bc,
    ushort_t* __restrict__ wt2,
    float* __restrict__ nq2, float* __restrict__ nd12, float* __restrict__ nd22,
    float* __restrict__ zero_base, float* __restrict__ pt5) {
  __shared__ float strip[64][33];
  int b = blockIdx.x;
  int tid = threadIdx.x;
  int wv = tid >> 6, lane = tid & 63;
  if (b < GATHER_BLOCKS) {
    int g = b * 4 + wv;
    if (g >= GATHER_ROWS) return;
    int t, row;
    if (g < 66)             { t = 0; row = g; }
    else if (g < 66 + 4098) { t = 1; row = g - 66; }
    else                    { t = 2; row = g - 4164; }
    const int* idx = t == 0 ? question : (t == 1 ? doc1 : doc2);
    int L = t == 0 ? QQ : DD;
    ushort_t* be = t == 0 ? qbe : (t == 1 ? d1be : d2be);
    ushort_t* bc = t == 0 ? qbc : (t == 1 ? d1bc : d2bc);
    float* nrm2 = t == 0 ? nq2 : (t == 1 ? nd12 : nd22);
    if (row == 0 || row == L + 1) {            // zero guard rows
      for (int i = lane; i < KP; i += 64) be[(size_t)row * KP + i] = 0;
      return;
    }
    int r = row - 1;
    const float* src = emb + (size_t)idx[r] * EE;
    float ss = 0.f;
    for (int i = lane; i < EE; i += 64) {
      float v = src[i];
      be[(size_t)row * KP + i] = f2bf(v);
      ss += v * v;
    }
    for (int i = EE + lane; i < KP; i += 64) {   // zero K-pads
      be[(size_t)row * KP + i] = 0;
      bc[(size_t)r * KP + i] = 0;
    }
    #pragma unroll
    for (int o = 32; o; o >>= 1) ss += __shfl_xor(ss, o);
    if (lane == 0) nrm2[r] = ss;                 // SQUARED norm
  } else if (b < GATHER_BLOCKS + WT_BLOCKS) {
    int f = (b - GATHER_BLOCKS) * 4 + wv;
    if (f >= 570) return;
    int ks = f % 10, n = (f / 10) % 19, tap = f / 190;
    int o = n * 16 + (lane & 15);
    int kbase = ks * 32 + (lane >> 4) * 8;
    ushort_t* dst = wt2 + (size_t)f * 512 + lane * 8;
    #pragma unroll
    for (int e = 0; e < 8; ++e) {
      int k = kbase + e;
      float v = (o < EE && k < EE) ? conv_w[((size_t)o * EE + k) * 3 + tap] : 0.f;
      dst[e] = f2bf(v);
    }
  } else if (b < GATHER_BLOCKS + WT_BLOCKS + ZERO_BLOCKS) {
    int i0 = (b - (GATHER_BLOCKS + WT_BLOCKS)) * 1024 + tid;
    #pragma unroll
    for (int j = 0; j < 4; ++j) {
      int i = i0 + j * 256;
      if (i < 8320) zero_base[i] = 0.f;   // nqc2,nd1c2,nd2c2,qwacc contiguous
    }
  } else {
    // ---- oh partial pooling: coalesced 32-row x 64-q chunk of doc_sim ----
    int ob = b - (GATHER_BLOCKS + WT_BLOCKS + ZERO_BLOCKS);
    int o = ob >> 7, chunk = ob & 127;
    int ps = o ? 3 : 0;
    const float* dsim = o ? doc2_sim : doc1_sim;   // [D][Q]
    int l0 = chunk * 32;
    int r = tid >> 3, q0 = (tid & 7) * 8;
    const float* srcp = dsim + (size_t)(l0 + r) * QQ + q0;
    f32x4 v0 = *(const f32x4*)srcp;
    f32x4 v1 = *(const f32x4*)(srcp + 4);
    #pragma unroll
    for (int e = 0; e < 4; ++e) strip[q0 + e][r] = v0[e];
    #pragma unroll
    for (int e = 0; e < 4; ++e) strip[q0 + 4 + e][r] = v1[e];
    __syncthreads();
    if (tid < 64) {
      float t5[5] = {-1e30f, -1e30f, -1e30f, -1e30f, -1e30f};
      #pragma unroll
      for (int l = 0; l < 32; ++l) top5_insert(t5, strip[tid][l]);
      float* dst = pt5 + (((size_t)ps * QQ + tid) * 128 + chunk) * 8;
      *(f32x4*)dst = (f32x4){t5[0], t5[1], t5[2], t5[3]};
      *(f32x4*)(dst + 4) = (f32x4){t5[4], -1e30f, -1e30f, -1e30f};
    }
  }
}

// ===== launch 2: conv1d(E,E,3,SAME)+bias+leaky+residual + norms^2 + qw-dot ==
__global__ __launch_bounds__(256) void conv_mfma(
    const ushort_t* __restrict__ wt2, const float* __restrict__ bias,
    const float* __restrict__ qw_w,
    const ushort_t* __restrict__ qbe, const ushort_t* __restrict__ d1be,
    const ushort_t* __restrict__ d2be,
    ushort_t* __restrict__ qbc, ushort_t* __restrict__ d1bc,
    ushort_t* __restrict__ d2bc,
    float* __restrict__ nqc2, float* __restrict__ nd1c2, float* __restrict__ nd2c2,
    float* __restrict__ qwacc) {
  __shared__ ushort_t lds[34 * LDSW];
  int bx = blockIdx.x;
  int t, m0, yh;
  if (bx < 4) { t = 0; m0 = (bx >> 1) * 32; yh = bx & 1; }
  else {
    int i = bx - 4;
    t = 1 + (i >> 8);
    int j = i & 255;
    m0 = (j >> 1) * 32; yh = j & 1;
  }
  const ushort_t* be = t == 0 ? qbe : (t == 1 ? d1be : d2be);
  ushort_t* bc = t == 0 ? qbc : (t == 1 ? d1bc : d2bc);
  float* nc2 = t == 0 ? nqc2 : (t == 1 ? nd1c2 : nd2c2);
  int tid = threadIdx.x;
  for (int s = tid; s < 34 * 40; s += 256) {
    int row = s / 40, col = s - row * 40;
    *(short8*)(&lds[row * LDSW + col * 8]) =
        *(const short8*)(be + (size_t)(m0 + row) * KP + col * 8);
  }
  __syncthreads();
  int wv = tid >> 6, lane = tid & 63, mrow = lane & 15, g = lane >> 4;
  int nstart, ncnt;
  if (yh == 0) { nstart = (wv < 2) ? 3 * wv : 2 * wv + 2; ncnt = (wv < 2) ? 3 : 2; }
  else         { nstart = (wv == 0) ? 10 : 2 * wv + 11;   ncnt = (wv == 0) ? 3 : 2; }
  f32x4 acc[3][2];
  #pragma unroll
  for (int j = 0; j < 3; ++j)
    #pragma unroll
    for (int h = 0; h < 2; ++h) acc[j][h] = (f32x4){0.f, 0.f, 0.f, 0.f};

  for (int tap = 0; tap < 3; ++tap) {
    const ushort_t* alo = &lds[(mrow + tap) * LDSW + g * 8];
    #pragma unroll
    for (int ks = 0; ks < 10; ++ks) {
      short8 a0 = *(const short8*)(alo + ks * 32);
      short8 a1 = *(const short8*)(alo + 16 * LDSW + ks * 32);
      #pragma unroll
      for (int j = 0; j < 3; ++j) {
        if (j < ncnt) {
          short8 bfr = *(const short8*)(wt2 +
              (size_t)((tap * 19 + nstart + j) * 10 + ks) * 512 + lane * 8);
          acc[j][0] = __builtin_amdgcn_mfma_f32_16x16x32_bf16(a0, bfr, acc[j][0], 0, 0, 0);
          acc[j][1] = __builtin_amdgcn_mfma_f32_16x16x32_bf16(a1, bfr, acc[j][1], 0, 0, 0);
        }
      }
    }
  }
  float ss[2][4] = {{0.f,0.f,0.f,0.f},{0.f,0.f,0.f,0.f}};
  float yq[2][4] = {{0.f,0.f,0.f,0.f},{0.f,0.f,0.f,0.f}};
  #pragma unroll
  for (int j = 0; j < 3; ++j) {
    if (j < ncnt) {
      int col = (nstart + j) * 16 + mrow;
      if (col < EE) {
        float bcol = bias[col];
        float qwc = (t == 0) ? qw_w[col] : 0.f;
        #pragma unroll
        for (int h = 0; h < 2; ++h) {
          #pragma unroll
          for (int r = 0; r < 4; ++r) {
            int lrow = h * 16 + g * 4 + r;
            float y = acc[j][h][r] + bcol;
            y = (y >= 0.f) ? y : NEG * y;
            y += bf2f(lds[(1 + lrow) * LDSW + col]);
            bc[(size_t)(m0 + lrow) * KP + col] = f2bf(y);
            ss[h][r] += y * y;
            if (t == 0) yq[h][r] += y * qwc;
          }
        }
      }
    }
  }
  #pragma unroll
  for (int h = 0; h < 2; ++h) {
    #pragma unroll
    for (int r = 0; r < 4; ++r) {
      float s = ss[h][r];
      s += __shfl_xor(s, 1); s += __shfl_xor(s, 2);
      s += __shfl_xor(s, 4); s += __shfl_xor(s, 8);
      if (mrow == 0) atomicAdd(&nc2[m0 + h * 16 + g * 4 + r], s);
      if (t == 0) {
        float sq = yq[h][r];
        sq += __shfl_xor(sq, 1); sq += __shfl_xor(sq, 2);
        sq += __shfl_xor(sq, 4); sq += __shfl_xor(sq, 8);
        if (mrow == 0) atomicAdd(&qwacc[m0 + h * 16 + g * 4 + r], sq);
      }
    }
  }
}

// ====== launch 3: sims GEMM + per-chunk partial top5 (no global sims) =======
// 512 blocks: s = b>>7 (0=ins_d1 1=ins_d2 2=sen_d1 3=sen_d2), chunk = b&127.
__global__ __launch_bounds__(256) void sim_pool(
    const ushort_t* __restrict__ qbe, const ushort_t* __restrict__ d1be,
    const ushort_t* __restrict__ d2be,
    const ushort_t* __restrict__ qbc, const ushort_t* __restrict__ d1bc,
    const ushort_t* __restrict__ d2bc,
    const float* __restrict__ nq2, const float* __restrict__ nd12,
    const float* __restrict__ nd22, const float* __restrict__ nqc2,
    const float* __restrict__ nd1c2, const float* __restrict__ nd2c2,
    float* __restrict__ pt5) {
  __shared__ ushort_t ldsB[32 * LDSW];
  __shared__ float strip[64][33];
  int s = blockIdx.x >> 7, chunk = blockIdx.x & 127;
  int ps = (s == 0) ? 1 : (s == 1) ? 4 : (s == 2) ? 2 : 5;
  int l0 = chunk * 32;
  const ushort_t* A = (s < 2) ? qbe + KP : qbc;
  const ushort_t* B = s == 0 ? d1be + KP : s == 1 ? d2be + KP
                    : s == 2 ? d1bc : d2bc;
  const float* na2 = (s < 2) ? nq2 : nqc2;
  const float* nb2 = s == 0 ? nd12 : s == 1 ? nd22 : s == 2 ? nd1c2 : nd2c2;
  int tid = threadIdx.x;
  for (int i = tid; i < 32 * 40; i += 256) {
    int row = i / 40, col = i - row * 40;
    *(short8*)(&ldsB[row * LDSW + col * 8]) =
        *(const short8*)(B + (size_t)(l0 + row) * KP + col * 8);
  }
  __syncthreads();
  int wv = tid >> 6, lane = tid & 63, mrow = lane & 15, g = lane >> 4;
  f32x4 acc[2];
  acc[0] = (f32x4){0.f, 0.f, 0.f, 0.f};
  acc[1] = (f32x4){0.f, 0.f, 0.f, 0.f};
  const ushort_t* arow = A + (size_t)(wv * 16 + mrow) * KP + g * 8;
  #pragma unroll
  for (int ks = 0; ks < 10; ++ks) {
    short8 a = *(const short8*)(arow + ks * 32);
    #pragma unroll
    for (int n = 0; n < 2; ++n) {
      short8 bfr = *(const short8*)(&ldsB[(n * 16 + mrow) * LDSW + g * 8 + ks * 32]);
      acc[n] = __builtin_amdgcn_mfma_f32_16x16x32_bf16(a, bfr, acc[n], 0, 0, 0);
    }
  }
  #pragma unroll
  for (int n = 0; n < 2; ++n) {
    int l = n * 16 + mrow;
    float inb = rsqrtf(nb2[l0 + l]);
    #pragma unroll
    for (int r = 0; r < 4; ++r) {
      int q = wv * 16 + g * 4 + r;
      strip[q][l] = acc[n][r] * rsqrtf(na2[q]) * inb;
    }
  }
  __syncthreads();
  if (tid < 64) {
    float t5[5] = {-1e30f, -1e30f, -1e30f, -1e30f, -1e30f};
    #pragma unroll
    for (int l = 0; l < 32; ++l) top5_insert(t5, strip[tid][l]);
    float* dst = pt5 + (((size_t)ps * QQ + tid) * 128 + chunk) * 8;
    *(f32x4*)dst = (f32x4){t5[0], t5[1], t5[2], t5[3]};
    *(f32x4*)(dst + 4) = (f32x4){t5[4], -1e30f, -1e30f, -1e30f};
  }
}

// ========= launch 4: merge 128 partials per (src,q) -> pool ================
// 96 blocks x 4 waves; wave = one (src,q). Coalesced 4KB read per wave.
__global__ __launch_bounds__(256) void merge(
    const float* __restrict__ pt5, float* __restrict__ pool) {
  int widx = blockIdx.x * 4 + (threadIdx.x >> 6);
  int lane = threadIdx.x & 63;
  int src = widx >> 6, q = widx & 63;
  const float* p0 = pt5 + (((size_t)src * QQ + q) * 128 + 2 * lane) * 8;
  float t5[5] = {-1e30f, -1e30f, -1e30f, -1e30f, -1e30f};
  #pragma unroll
  for (int c = 0; c < 2; ++c)
    #pragma unroll
    for (int j = 0; j < 5; ++j) top5_insert(t5, p0[c * 8 + j]);
  #pragma unroll
  for (int mask = 1; mask < 64; mask <<= 1) {
    float a[5], bb[5];
    #pragma unroll
    for (int j = 0; j < 5; ++j) { a[j] = t5[j]; bb[j] = __shfl_xor(t5[j], mask); }
    int ia = 0, ib = 0;
    #pragma unroll
    for (int j = 0; j < 5; ++j) t5[j] = (a[ia] >= bb[ib]) ? a[ia++] : bb[ib++];
  }
  if (lane == 0) {
    float sm = t5[0] + t5[1] + t5[2] + t5[3] + t5[4];
    pool[((size_t)src * QQ + q) * 2 + 0] = t5[0];
    pool[((size_t)src * QQ + q) * 2 + 1] = sm * 0.2f;
  }
}

// ================= launch 5: softmax + MLP + epilogue (one wave) ============
__global__ void final_kernel(
    const float* __restrict__ qwacc, const float* __restrict__ idf,
    const int* __restrict__ question, const float* __restrict__ qw_w,
    const float* __restrict__ qw_b, const float* __restrict__ pool,
    const float* __restrict__ lin1_w, const float* __restrict__ lin2_w,
    const float* __restrict__ out_w, const float* __restrict__ gaf,
    const float* __restrict__ baf, float* __restrict__ out5) {
  int q = threadIdx.x;  // 64 threads = one wave
  float s = qwacc[q] + qw_b[0] + idf[question[q]] * qw_w[EE];
  float m = s;
  #pragma unroll
  for (int o = 32; o; o >>= 1) m = fmaxf(m, __shfl_xor(m, o));
  float e = expf(s - m);
  float se = e;
  #pragma unroll
  for (int o = 32; o; o >>= 1) se += __shfl_xor(se, o);
  float qwgt = e / se;

  float emit[2];
  for (int doc = 0; doc < 2; ++doc) {
    float temp[6];
    #pragma unroll
    for (int j = 0; j < 3; ++j) {
      temp[2 * j]     = pool[(((size_t)doc * 3 + j) * QQ + q) * 2 + 0];
      temp[2 * j + 1] = pool[(((size_t)doc * 3 + j) * QQ + q) * 2 + 1];
    }
    float lo = 0.f;
    #pragma unroll
    for (int r = 0; r < 8; ++r) {
      float h = 0.f;
      #pragma unroll
      for (int c = 0; c < 6; ++c) h += lin1_w[r * 6 + c] * temp[c];
      h = (h >= 0.f) ? h : NEG * h;
      lo += lin2_w[r] * h;
    }
    lo *= qwgt;
    #pragma unroll
    for (int o = 32; o; o >>= 1) lo += __shfl_xor(lo, o);
    emit[doc] = lo / (float)QQ;
  }
  if (q == 0) {
    float good = out_w[0] * gaf[0] + out_w[1] * gaf[1] + out_w[2] * gaf[2] +
                 out_w[3] * gaf[3] + out_w[4] * emit[0];
    float bad  = out_w[0] * baf[0] + out_w[1] * baf[1] + out_w[2] * baf[2] +
                 out_w[3] * baf[3] + out_w[4] * emit[1];
    float l1 = fmaxf(0.f, -(good - bad) + 1.f);
    out5[0] = l1; out5[1] = good; out5[2] = bad; out5[3] = l1; out5[4] = l1;
  }
}

extern "C" void kernel_launch(void* const* d_in, const int* in_sizes, int n_in,
                              void* d_out, int out_size, void* d_ws, size_t ws_size,
                              hipStream_t stream) {
  (void)in_sizes; (void)n_in; (void)out_size; (void)ws_size;
  const int* question   = (const int*)d_in[0];
  const int* doc1       = (const int*)d_in[1];
  const int* doc2       = (const int*)d_in[2];
  const float* doc1_sim = (const float*)d_in[3];
  const float* doc2_sim = (const float*)d_in[4];
  const float* gaf      = (const float*)d_in[5];
  const float* baf      = (const float*)d_in[6];
  const float* emb      = (const float*)d_in[7];
  const float* idf      = (const float*)d_in[8];
  const float* conv_w   = (const float*)d_in[9];
  const float* conv_b   = (const float*)d_in[10];
  const float* qw_w     = (const float*)d_in[11];
  const float* qw_b     = (const float*)d_in[12];
  const float* lin1_w   = (const float*)d_in[13];
  const float* lin2_w   = (const float*)d_in[14];
  const float* out_w    = (const float*)d_in[15];
  float* out = (float*)d_out;

  char* p = (char*)d_ws;
  ushort_t* qbe  = (ushort_t*)p; p += (size_t)(QQ + 2) * KP * 2;
  ushort_t* d1be = (ushort_t*)p; p += (size_t)(DD + 2) * KP * 2;
  ushort_t* d2be = (ushort_t*)p; p += (size_t)(DD + 2) * KP * 2;
  ushort_t* qbc  = (ushort_t*)p; p += (size_t)QQ * KP * 2;
  ushort_t* d1bc = (ushort_t*)p; p += (size_t)DD * KP * 2;
  ushort_t* d2bc = (ushort_t*)p; p += (size_t)DD * KP * 2;
  ushort_t* wt2  = (ushort_t*)p; p += (size_t)570 * 512 * 2;
  float* nq2   = (float*)p; p += QQ * 4;
  float* nd12  = (float*)p; p += DD * 4;
  float* nd22  = (float*)p; p += DD * 4;
  // zeroed-each-call accumulator block (contiguous 8320 floats)
  float* nqc2  = (float*)p; p += QQ * 4;
  float* nd1c2 = (float*)p; p += DD * 4;
  float* nd2c2 = (float*)p; p += DD * 4;
  float* qwacc = (float*)p; p += QQ * 4;
  float* pt5   = (float*)p; p += (size_t)6 * QQ * 128 * 8 * 4;

  float* pool  = (float*)p; p += 6 * QQ * 2 * 4;

  prep<<<PREP_BLOCKS, 256, 0, stream>>>(
      emb, question, doc1, doc2, conv_w, doc1_sim, doc2_sim,
      qbe, d1be, d2be, qbc, d1bc, d2bc, wt2,
      nq2, nd12, nd22, nqc2, pt5);

  conv_mfma<<<516, 256, 0, stream>>>(
      wt2, conv_b, qw_w, qbe, d1be, d2be, qbc, d1bc, d2bc,
      nqc2, nd1c2, nd2c2, qwacc);

  sim_pool<<<512, 256, 0, stream>>>(
      qbe, d1be, d2be, qbc, d1bc, d2bc,
      nq2, nd12, nd22, nqc2, nd1c2, nd2c2, pt5);

  merge<<<96, 256, 0, stream>>>(pt5, pool);

  final_kernel<<<1, 64, 0, stream>>>(qwacc, idf, question, qw_w, qw_b, pool,
                                     lin1_w, lin2_w, out_w, gaf, baf, out);
}